// Round 8
// baseline (175.546 us; speedup 1.0000x reference)
//
#include <hip/hip_runtime.h>

// LIF layer fused step, f32.
// Inputs: input_spikes[8192], voltages[1,8192], synapses[8192,8192], weights[8192,8192]
// Outputs (concat in d_out): spikes[8192] (0/1 f32), v_new[8192], syn[8192,8192]
//
// R1-R7 evidence: k1 is pinned at ~2.98 TB/s HBM-side across 5 structurally
// different schedules (occupancy 18-74%, VGPR 12-64, NT/non-NT, strided/
// contiguous). Treat the rate as a mixed-stream ceiling; minimize HBM bytes
// instead: partials shrunk 16.8->4.2 MB (cache-resident), tail fused to one
// kernel.

#define V_DECAY 0.99004983374916811f   // exp(-1/100)
#define S_DECAY 0.98019867330675525f   // exp(-1/50)
#define THRESH  1.0f

constexpr int N_IN  = 8192;
constexpr int N_OUT = 8192;
constexpr int COLSPLIT = 4;            // column quarters per row
constexpr int COLS = N_OUT / COLSPLIT; // 2048 = 256 thr * 4 f32 * 2 steps

typedef float f32x4 __attribute__((ext_vector_type(4)));

// Kernel 1: block = (column quarter ct, row chunk rc). Simple unrolled walk;
// per-(chunk,column) partial sums -> d_ws.
__global__ __launch_bounds__(256) void lif_syn_kernel(
    const float* __restrict__ input_spikes,
    const float* __restrict__ synapses,
    const float* __restrict__ weights,
    float* __restrict__ syn_out,
    float* __restrict__ partials,       // [chunks][N_OUT]
    int rowsPerChunk)
{
    const int ct   = blockIdx.x % COLSPLIT;
    const int rc   = blockIdx.x / COLSPLIT;
    const int c0   = ct * COLS + threadIdx.x * 4;
    const int row0 = rc * rowsPerChunk;

    f32x4 acc0 = (f32x4)(0.f), acc1 = (f32x4)(0.f);

    #pragma unroll 4
    for (int r = 0; r < rowsPerChunk; ++r) {
        const int row    = row0 + r;
        const float sp   = input_spikes[row];           // uniform -> s_load
        const size_t b   = (size_t)row * N_OUT + c0;
        const f32x4 s0 = *(const f32x4*)(synapses + b);
        const f32x4 s1 = *(const f32x4*)(synapses + b + 1024);
        const f32x4 w0 = *(const f32x4*)(weights  + b);
        const f32x4 w1 = *(const f32x4*)(weights  + b + 1024);
        const f32x4 o0 = s0 * S_DECAY + w0 * sp;
        const f32x4 o1 = s1 * S_DECAY + w1 * sp;
        *(f32x4*)(syn_out + b)        = o0;
        *(f32x4*)(syn_out + b + 1024) = o1;
        acc0 += o0; acc1 += o1;
    }

    const size_t pbase = (size_t)rc * N_OUT + c0;
    *(f32x4*)(partials + pbase)        = acc0;
    *(f32x4*)(partials + pbase + 1024) = acc1;
}

// Kernel 2: single fused tail — reduce all partials rows + voltage/spike
// update. partials is 4.2 MB, freshly written -> served from L2/L3.
__global__ __launch_bounds__(256) void lif_v_kernel(
    const float* __restrict__ voltages,
    const float* __restrict__ partials,
    float* __restrict__ out,            // [0,N)=spikes, [N,2N)=v_new
    int nChunks)
{
    const int c = blockIdx.x * blockDim.x + threadIdx.x;
    const float v     = voltages[c] * V_DECAY;
    const float spike = (v >= THRESH) ? 1.0f : 0.0f;
    float sum = 0.f;
    #pragma unroll 8
    for (int g = 0; g < nChunks; ++g)
        sum += partials[(size_t)g * N_OUT + c];          // coalesced
    out[c]         = spike;
    out[N_OUT + c] = v + sum - spike * THRESH;
}

extern "C" void kernel_launch(void* const* d_in, const int* in_sizes, int n_in,
                              void* d_out, int out_size, void* d_ws, size_t ws_size,
                              hipStream_t stream) {
    const float* input_spikes = (const float*)d_in[0];
    const float* voltages     = (const float*)d_in[1];
    const float* synapses     = (const float*)d_in[2];
    const float* weights      = (const float*)d_in[3];

    float* out      = (float*)d_out;
    float* syn_out  = out + 2 * N_OUT;
    float* partials = (float*)d_ws;

    // 128 chunks x 64 rows: partials = 4.2 MB (cache-resident), grid = 512
    // blocks (2/CU, 8 waves/CU — R6-proven sufficient for the rate ceiling).
    int chunks = 128;
    while (chunks > 1 && (size_t)chunks * N_OUT * sizeof(float) > ws_size)
        chunks >>= 1;
    const int rowsPerChunk = N_IN / chunks;

    lif_syn_kernel<<<dim3(COLSPLIT * chunks), dim3(256), 0, stream>>>(
        input_spikes, synapses, weights, syn_out, partials, rowsPerChunk);

    lif_v_kernel<<<dim3(N_OUT / 256), dim3(256), 0, stream>>>(
        voltages, partials, out, chunks);
}

// Round 9
// 170.567 us; speedup vs baseline: 1.0292x; 1.0292x over previous
//
#include <hip/hip_runtime.h>

// LIF layer fused step, f32.
// Inputs: input_spikes[8192], voltages[1,8192], synapses[8192,8192], weights[8192,8192]
// Outputs (concat in d_out): spikes[8192] (0/1 f32), v_new[8192], syn[8192,8192]
//
// R1-R8 evidence: k1 HBM-side rate is invariant (~2.9-3.0 TB/s profiled,
// ~3.5 TB/s timed) across six schedules (occupancy 18-74%, VGPR 12-64,
// NT/non-NT, strided/contiguous, pipelined/pinned). HBM bytes are at the
// floor (L3 absorbs half the 512 MB input re-read; fetch ~262 MB, write
// ~266 MB compulsory). R7 config = best timed (160.1 us). This restores it.

#define V_DECAY 0.99004983374916811f   // exp(-1/100)
#define S_DECAY 0.98019867330675525f   // exp(-1/50)
#define THRESH  1.0f

constexpr int N_IN  = 8192;
constexpr int N_OUT = 8192;
constexpr int HALF  = 4096;            // columns per block (256 thr * 4 f * 4 steps)

typedef float f32x4 __attribute__((ext_vector_type(4)));

// One row-half = 8 dwordx4 loads (4 synapse + 4 weight steps, stride 4 KB).
#define DECL_SET(P) f32x4 P##s0, P##s1, P##s2, P##s3, P##w0, P##w1, P##w2, P##w3; float P##sp;

#define LOAD_SET(P, ROW) do {                                        \
    const size_t b_ = (size_t)(ROW) * N_OUT + c0;                    \
    P##s0 = *(const f32x4*)(synapses + b_);                          \
    P##s1 = *(const f32x4*)(synapses + b_ + 1024);                   \
    P##s2 = *(const f32x4*)(synapses + b_ + 2048);                   \
    P##s3 = *(const f32x4*)(synapses + b_ + 3072);                   \
    P##w0 = *(const f32x4*)(weights  + b_);                          \
    P##w1 = *(const f32x4*)(weights  + b_ + 1024);                   \
    P##w2 = *(const f32x4*)(weights  + b_ + 2048);                   \
    P##w3 = *(const f32x4*)(weights  + b_ + 3072);                   \
    P##sp = input_spikes[ROW];                                       \
} while (0)

// Regalloc cannot cheat an asm that reads all 8 results: all 8 loads must be
// issued and live here.
#define PIN_SET(P)                                                   \
    asm volatile("" : "+v"(P##s0), "+v"(P##s1), "+v"(P##s2), "+v"(P##s3), \
                      "+v"(P##w0), "+v"(P##w1), "+v"(P##w2), "+v"(P##w3))

#define COMP_SET(P, ROW) do {                                        \
    const size_t b_ = (size_t)(ROW) * N_OUT + c0;                    \
    const f32x4 o0 = P##s0 * S_DECAY + P##w0 * P##sp;                \
    const f32x4 o1 = P##s1 * S_DECAY + P##w1 * P##sp;                \
    const f32x4 o2 = P##s2 * S_DECAY + P##w2 * P##sp;                \
    const f32x4 o3 = P##s3 * S_DECAY + P##w3 * P##sp;                \
    *(f32x4*)(syn_out + b_)        = o0;                             \
    *(f32x4*)(syn_out + b_ + 1024) = o1;                             \
    *(f32x4*)(syn_out + b_ + 2048) = o2;                             \
    *(f32x4*)(syn_out + b_ + 3072) = o3;                             \
    acc0 += o0; acc1 += o1; acc2 += o2; acc3 += o3;                  \
} while (0)

// Kernel 1: block = (column half h, 16-row chunk rc). Two-row software
// pipeline: while computing row set A (pinned live by asm), row set B's 8
// loads are already in flight.
__global__ __launch_bounds__(256, 4) void lif_syn_kernel(
    const float* __restrict__ input_spikes,
    const float* __restrict__ synapses,
    const float* __restrict__ weights,
    float* __restrict__ syn_out,
    float* __restrict__ partials,       // [chunks][N_OUT]
    int rowsPerChunk)                   // multiple of 16
{
    const int h    = blockIdx.x & 1;
    const int rc   = blockIdx.x >> 1;
    const int c0   = h * HALF + threadIdx.x * 4;
    const int row0 = rc * rowsPerChunk;

    f32x4 acc0 = (f32x4)(0.f), acc1 = (f32x4)(0.f),
          acc2 = (f32x4)(0.f), acc3 = (f32x4)(0.f);

    DECL_SET(A); DECL_SET(B);

    for (int rr = 0; rr < rowsPerChunk; rr += 16) {
        const int rbase = row0 + rr;
        LOAD_SET(A, rbase);
        #pragma unroll
        for (int r = 0; r < 16; r += 2) {
            LOAD_SET(B, rbase + r + 1);
            __builtin_amdgcn_sched_barrier(0);
            PIN_SET(A);
            COMP_SET(A, rbase + r);
            if (r + 2 < 16) LOAD_SET(A, rbase + r + 2);
            __builtin_amdgcn_sched_barrier(0);
            PIN_SET(B);
            COMP_SET(B, rbase + r + 1);
        }
    }

    const size_t pbase = (size_t)rc * N_OUT + c0;
    *(f32x4*)(partials + pbase)        = acc0;
    *(f32x4*)(partials + pbase + 1024) = acc1;
    *(f32x4*)(partials + pbase + 2048) = acc2;
    *(f32x4*)(partials + pbase + 3072) = acc3;
}

// Kernel 2a: 16:1 reduction. Group g reads rows [16g, 16g+16), writes row 16g
// (its OWN first input row) — no cross-group overlap, deterministic.
__global__ __launch_bounds__(256) void lif_reduce_kernel(
    float* __restrict__ partials)
{
    const int ctiles = N_OUT / 256;                    // 32
    const int c = (blockIdx.x % ctiles) * 256 + threadIdx.x;
    const int g = blockIdx.x / ctiles;
    float sum = 0.f;
    #pragma unroll
    for (int k = 0; k < 16; ++k)
        sum += partials[(size_t)(g * 16 + k) * N_OUT + c];
    partials[(size_t)(g * 16) * N_OUT + c] = sum;
}

// Kernel 2b: final reduce (rows at stride rowStride) + voltage/spike update.
__global__ __launch_bounds__(256) void lif_v_kernel(
    const float* __restrict__ voltages,
    const float* __restrict__ partials,
    float* __restrict__ out,            // [0,N)=spikes, [N,2N)=v_new
    int nGroups, int rowStride)
{
    const int c = blockIdx.x * blockDim.x + threadIdx.x;
    const float v     = voltages[c] * V_DECAY;
    const float spike = (v >= THRESH) ? 1.0f : 0.0f;
    float sum = 0.f;
    #pragma unroll 8
    for (int g = 0; g < nGroups; ++g)
        sum += partials[(size_t)(g * rowStride) * N_OUT + c];
    out[c]         = spike;
    out[N_OUT + c] = v + sum - spike * THRESH;
}

extern "C" void kernel_launch(void* const* d_in, const int* in_sizes, int n_in,
                              void* d_out, int out_size, void* d_ws, size_t ws_size,
                              hipStream_t stream) {
    const float* input_spikes = (const float*)d_in[0];
    const float* voltages     = (const float*)d_in[1];
    const float* synapses     = (const float*)d_in[2];
    const float* weights      = (const float*)d_in[3];

    float* out      = (float*)d_out;
    float* syn_out  = out + 2 * N_OUT;
    float* partials = (float*)d_ws;

    // 512 chunks x 16 rows (16.8 MB ws — fits, proven R4-R7). Fallback halves
    // chunks; rowsPerChunk stays a multiple of 16.
    int chunks = 512;
    while (chunks > 1 && (size_t)chunks * N_OUT * sizeof(float) > ws_size)
        chunks >>= 1;
    const int rowsPerChunk = N_IN / chunks;

    lif_syn_kernel<<<dim3(2 * chunks), dim3(256), 0, stream>>>(
        input_spikes, synapses, weights, syn_out, partials, rowsPerChunk);

    if (chunks >= 16) {
        lif_reduce_kernel<<<dim3((N_OUT / 256) * (chunks / 16)), dim3(256), 0,
                            stream>>>(partials);
        lif_v_kernel<<<dim3(N_OUT / 256), dim3(256), 0, stream>>>(
            voltages, partials, out, chunks / 16, 16);
    } else {
        lif_v_kernel<<<dim3(N_OUT / 256), dim3(256), 0, stream>>>(
            voltages, partials, out, chunks, 1);
    }
}